// Round 3
// baseline (135.517 us; speedup 1.0000x reference)
//
#include <hip/hip_runtime.h>
#include <math.h>

#define DIM 128
#define N_PTS 512
#define K_NEIGH 16
#define POS_HID 64
#define ATTN_HID 512

typedef __attribute__((ext_vector_type(8))) short short8;
typedef __attribute__((ext_vector_type(4))) float f32x4;
typedef unsigned short us;
typedef unsigned long long ull;

__device__ __forceinline__ us f2b(float f) {
    unsigned int u = __builtin_bit_cast(unsigned int, f);
    u += 0x7fffu + ((u >> 16) & 1u);          // RNE
    return (us)(u >> 16);
}

__device__ __forceinline__ ull shflx64(ull v, int m) {
    int lo = __shfl_xor((int)(unsigned int)v, m);
    int hi = __shfl_xor((int)(unsigned int)(v >> 32), m);
    return ((ull)(unsigned int)hi << 32) | (unsigned int)lo;
}

// ---------------------------------------------------------------------------
// Pack all weights (fp32) into bf16 B-fragment order for mfma_16x16x32_bf16:
// B[k][n] -> lane l=(k/8%4)*16+(n%16), elem j=k%8, frag=(ks*NT+nt);
// packed[(frag*64+l)*8+j].  p0=wqkv(128x384), p1=aw1(128x512),
// p2=aw2(512x128), p3=pw2(64x128).
// ---------------------------------------------------------------------------
__global__ void pack_kernel(const float* __restrict__ wqkv,
                            const float* __restrict__ aw1,
                            const float* __restrict__ aw2,
                            const float* __restrict__ pw2,
                            us* __restrict__ p0, us* __restrict__ p1,
                            us* __restrict__ p2, us* __restrict__ p3) {
    int t = blockIdx.x * 256 + threadIdx.x;
    if (t < 49152) {                        // wqkv: nt 0..23, ks 0..3
        int j = t & 7, l = (t >> 3) & 63, rem = t >> 9;
        int nt = rem % 24, ks = rem / 24;
        int k = ks * 32 + (l >> 4) * 8 + j, n = nt * 16 + (l & 15);
        p0[t] = f2b(wqkv[k * 384 + n]);
    } else if (t < 114688) {                // aw1: ks 0..3, nt 0..31
        int u = t - 49152;
        int j = u & 7, l = (u >> 3) & 63, nt = (u >> 9) & 31, ks = u >> 14;
        int k = ks * 32 + (l >> 4) * 8 + j, n = nt * 16 + (l & 15);
        p1[u] = f2b(aw1[k * ATTN_HID + n]);
    } else if (t < 180224) {                // aw2: ch 0..15, nt 0..7
        int u = t - 114688;
        int j = u & 7, l = (u >> 3) & 63, nt = (u >> 9) & 7, ch = u >> 12;
        int k = ch * 32 + (l >> 4) * 8 + j, n = nt * 16 + (l & 15);
        p2[u] = f2b(aw2[k * DIM + n]);
    } else if (t < 188416) {                // pw2: ks 0..1, nt 0..7
        int u = t - 180224;
        int j = u & 7, l = (u >> 3) & 63, nt = (u >> 9) & 7, ks = u >> 12;
        int k = ks * 32 + (l >> 4) * 8 + j, n = nt * 16 + (l & 15);
        p3[u] = f2b(pw2[k * DIM + n]);
    }
}

// ---------------------------------------------------------------------------
// qkv via MFMA: one wave per 16-point M-tile, N=384, K=128.
// ---------------------------------------------------------------------------
__global__ __launch_bounds__(64)
void qkv_mfma_kernel(const float* __restrict__ x,
                     const us* __restrict__ p0,
                     float* __restrict__ qkv) {
    __shared__ __align__(16) us xA[16][136];
    const int lane = threadIdx.x;
    const int n0 = blockIdx.x * 16;           // global point base
    const int b = n0 >> 9, nn = n0 & (N_PTS - 1);
#pragma unroll
    for (int rr = 0; rr < 32; ++rr) {
        int id = rr * 64 + lane;
        int d = id >> 4, i = id & 15;
        xA[i][d] = f2b(x[(b * DIM + d) * N_PTS + nn + i]);
    }
    __syncthreads();
    const int quad = lane >> 4, lq = lane & 15;
    short8 a[4];
#pragma unroll
    for (int ks = 0; ks < 4; ++ks)
        a[ks] = *(const short8*)&xA[lq][ks * 32 + quad * 8];
    for (int nt = 0; nt < 24; ++nt) {
        f32x4 acc = {0.f, 0.f, 0.f, 0.f};
#pragma unroll
        for (int ks = 0; ks < 4; ++ks) {
            const short8 bf = *(const short8*)(p0 + (size_t)((ks * 24 + nt) * 64 + lane) * 8);
            acc = __builtin_amdgcn_mfma_f32_16x16x32_bf16(a[ks], bf, acc, 0, 0, 0);
        }
#pragma unroll
        for (int r = 0; r < 4; ++r)
            qkv[(size_t)(n0 + quad * 4 + r) * 384 + nt * 16 + lq] = acc[r];
    }
}

// ---------------------------------------------------------------------------
// Fused: shuffle-only top-16 + pos-MLP (into A-frags) + pe GEMM + hin/vg +
// interleaved layer1/layer2 MFMA chain + softmax + store.
// 2 points per wave (each B-frag feeds 2 MFMAs), 2 waves per block,
// 256 blocks -> 1 block/CU, per-CU L1 B-traffic ~540 KB.
// ab2 skipped: softmax over k is invariant to a per-channel constant.
// ---------------------------------------------------------------------------
__global__ __launch_bounds__(128)
void attn_fused_kernel(const float* __restrict__ pos,
                       const float* __restrict__ qkv,
                       const float* __restrict__ pw1,
                       const float* __restrict__ pb1,
                       const float* __restrict__ pb2,
                       const us* __restrict__ p1,
                       const us* __restrict__ p2,
                       const us* __restrict__ p3,
                       const float* __restrict__ ab1,
                       float* __restrict__ out) {
    __shared__ __align__(16) us hinA[2][2][16][136];  // 17.4 KB
    __shared__ __align__(16) us h1s[2][2][16][40];    //  5.1 KB
    __shared__ int nbrs[2][2][16];                    //  256 B

    const int tid = threadIdx.x;
    const int w = tid >> 6, lane = tid & 63, quad = lane >> 4, lq = lane & 15;
    const int g0 = blockIdx.x * 4 + w * 2;

    // ---- top-16 per point: u64 key = (dist_bits<<32)|j, butterfly min ----
#pragma unroll
    for (int p = 0; p < 2; ++p) {
        const int g = g0 + p, b = g >> 9;
        const float pix = pos[g * 3 + 0], piy = pos[g * 3 + 1], piz = pos[g * 3 + 2];
        float d2[8];
#pragma unroll
        for (int rr = 0; rr < 8; ++rr) {
            int j = rr * 64 + lane;
            float dx = pix - pos[(b * N_PTS + j) * 3 + 0];
            float dy = piy - pos[(b * N_PTS + j) * 3 + 1];
            float dz = piz - pos[(b * N_PTS + j) * 3 + 2];
            d2[rr] = dx * dx + dy * dy + dz * dz;
        }
        for (int r = 0; r < K_NEIGH; ++r) {
            ull key = ~0ULL;
#pragma unroll
            for (int rr = 0; rr < 8; ++rr) {
                unsigned int fb = __builtin_bit_cast(unsigned int, d2[rr]);
                ull k2 = ((ull)fb << 32) | (unsigned int)(rr * 64 + lane);
                key = k2 < key ? k2 : key;
            }
#pragma unroll
            for (int off = 32; off > 0; off >>= 1) {
                ull o = shflx64(key, off);
                key = o < key ? o : key;
            }
            unsigned int jw = (unsigned int)key;
            if (lane == 0) nbrs[w][p][r] = (int)jw;
            if (lane == (int)(jw & 63)) d2[jw >> 6] = __builtin_inff();
        }
    }

    // ---- pos-MLP hidden -> A-frag registers (k = ks*32 + quad*8 + jj) ----
    short8 pha[2][2];
#pragma unroll
    for (int p = 0; p < 2; ++p) {
        const int g = g0 + p, b = g >> 9;
        const int jn = nbrs[w][p][lq];
        float rx = pos[g * 3 + 0] - pos[(b * N_PTS + jn) * 3 + 0];
        float ry = pos[g * 3 + 1] - pos[(b * N_PTS + jn) * 3 + 1];
        float rz = pos[g * 3 + 2] - pos[(b * N_PTS + jn) * 3 + 2];
#pragma unroll
        for (int ks = 0; ks < 2; ++ks) {
            short8 f;
#pragma unroll
            for (int jj = 0; jj < 8; ++jj) {
                int c = ks * 32 + quad * 8 + jj;
                float h = rx * pw1[c] + ry * pw1[64 + c] + rz * pw1[128 + c] + pb1[c];
                f[jj] = (short)f2b(fmaxf(h, 0.f));
            }
            pha[p][ks] = f;
        }
    }

    // ---- pe = ph @ pw2 + pb2 (M=16,K=64,N=128); B-frag shared by 2 pts ----
    f32x4 pe[2][8];
#pragma unroll
    for (int nt = 0; nt < 8; ++nt) {
        const short8 b0 = *(const short8*)(p3 + (size_t)((0 * 8 + nt) * 64 + lane) * 8);
        const short8 b1 = *(const short8*)(p3 + (size_t)((1 * 8 + nt) * 64 + lane) * 8);
        float bias = pb2[nt * 16 + lq];
#pragma unroll
        for (int p = 0; p < 2; ++p) {
            f32x4 acc = {0.f, 0.f, 0.f, 0.f};
            acc = __builtin_amdgcn_mfma_f32_16x16x32_bf16(pha[p][0], b0, acc, 0, 0, 0);
            acc = __builtin_amdgcn_mfma_f32_16x16x32_bf16(pha[p][1], b1, acc, 0, 0, 0);
#pragma unroll
            for (int r = 0; r < 4; ++r) pe[p][nt][r] = acc[r] + bias;
        }
    }

    // ---- hin = q_i - k_j + pe -> LDS (bf16 A-layout); vg = v_j + pe ----
    f32x4 vg[2][8];
#pragma unroll
    for (int p = 0; p < 2; ++p) {
        const int g = g0 + p, b = g >> 9;
        int jr[4];
#pragma unroll
        for (int r = 0; r < 4; ++r) jr[r] = nbrs[w][p][quad * 4 + r];
#pragma unroll
        for (int nt = 0; nt < 8; ++nt) {
            int d = nt * 16 + lq;
            float qv = qkv[(size_t)g * 384 + d];
#pragma unroll
            for (int r = 0; r < 4; ++r) {
                const float* kv = qkv + (size_t)(b * N_PTS + jr[r]) * 384;
                float pp = pe[p][nt][r];
                hinA[w][p][quad * 4 + r][d] = f2b(qv - kv[128 + d] + pp);
                vg[p][nt][r] = kv[256 + d] + pp;
            }
        }
    }

    // ---- layer1 + layer2 interleaved in 32-col chunks ----
    short8 a1f[2][4];
#pragma unroll
    for (int p = 0; p < 2; ++p)
#pragma unroll
        for (int ks = 0; ks < 4; ++ks)
            a1f[p][ks] = *(const short8*)&hinA[w][p][lq][ks * 32 + quad * 8];

    f32x4 c2[2][8];
#pragma unroll
    for (int p = 0; p < 2; ++p)
#pragma unroll
        for (int nt = 0; nt < 8; ++nt) c2[p][nt] = (f32x4){0.f, 0.f, 0.f, 0.f};

    for (int ch = 0; ch < 16; ++ch) {
#pragma unroll
        for (int t = 0; t < 2; ++t) {
            int nt = ch * 2 + t;
            short8 bf[4];
#pragma unroll
            for (int ks = 0; ks < 4; ++ks)
                bf[ks] = *(const short8*)(p1 + (size_t)(((ks << 5) + nt) * 64 + lane) * 8);
            float bias = ab1[nt * 16 + lq];
#pragma unroll
            for (int p = 0; p < 2; ++p) {
                f32x4 acc = {0.f, 0.f, 0.f, 0.f};
#pragma unroll
                for (int ks = 0; ks < 4; ++ks)
                    acc = __builtin_amdgcn_mfma_f32_16x16x32_bf16(a1f[p][ks], bf[ks], acc, 0, 0, 0);
#pragma unroll
                for (int r = 0; r < 4; ++r)
                    h1s[w][p][quad * 4 + r][t * 16 + lq] = f2b(fmaxf(acc[r] + bias, 0.f));
            }
        }
        short8 a2[2];
#pragma unroll
        for (int p = 0; p < 2; ++p)
            a2[p] = *(const short8*)&h1s[w][p][lq][quad * 8];
#pragma unroll
        for (int nt2 = 0; nt2 < 8; ++nt2) {
            const short8 bf2 = *(const short8*)(p2 + (size_t)(((ch << 3) + nt2) * 64 + lane) * 8);
#pragma unroll
            for (int p = 0; p < 2; ++p)
                c2[p][nt2] = __builtin_amdgcn_mfma_f32_16x16x32_bf16(a2[p], bf2, c2[p][nt2], 0, 0, 0);
        }
    }

    // ---- softmax over the 16 neighbors + aggregate + store ----
#pragma unroll
    for (int p = 0; p < 2; ++p) {
        const int g = g0 + p, b = g >> 9, n = g & (N_PTS - 1);
#pragma unroll
        for (int nt2 = 0; nt2 < 8; ++nt2) {
            f32x4 s4 = c2[p][nt2];
            float m = fmaxf(fmaxf(s4[0], s4[1]), fmaxf(s4[2], s4[3]));
            m = fmaxf(m, __shfl_xor(m, 16));
            m = fmaxf(m, __shfl_xor(m, 32));
            float e0 = __expf(s4[0] - m), e1 = __expf(s4[1] - m);
            float e2 = __expf(s4[2] - m), e3 = __expf(s4[3] - m);
            float s = e0 + e1 + e2 + e3;
            f32x4 v4 = vg[p][nt2];
            float a = e0 * v4[0] + e1 * v4[1] + e2 * v4[2] + e3 * v4[3];
            s += __shfl_xor(s, 16); s += __shfl_xor(s, 32);
            a += __shfl_xor(a, 16); a += __shfl_xor(a, 32);
            if (quad == 0)
                out[(size_t)(b * DIM + nt2 * 16 + lq) * N_PTS + n] = a / s;
        }
    }
}

extern "C" void kernel_launch(void* const* d_in, const int* in_sizes, int n_in,
                              void* d_out, int out_size, void* d_ws, size_t ws_size,
                              hipStream_t stream) {
    const float* x    = (const float*)d_in[0];
    const float* pos  = (const float*)d_in[1];
    const float* wqkv = (const float*)d_in[2];
    const float* pw1  = (const float*)d_in[3];
    const float* pb1  = (const float*)d_in[4];
    const float* pw2  = (const float*)d_in[5];
    const float* pb2  = (const float*)d_in[6];
    const float* aw1  = (const float*)d_in[7];
    const float* ab1  = (const float*)d_in[8];
    const float* aw2  = (const float*)d_in[9];
    // ab2 unused: softmax over k is invariant to per-channel bias.
    float* out = (float*)d_out;

    int B = in_sizes[0] / (DIM * N_PTS);
    int npts = B * N_PTS;                    // 1024

    char* ws = (char*)d_ws;
    float* qkv = (float*)ws;                               // npts*384 f32
    us* p0 = (us*)(ws + (size_t)npts * 384 * 4);           // 49152
    us* p1 = p0 + 49152;                                   // 65536
    us* p2 = p1 + 65536;                                   // 65536
    us* p3 = p2 + 65536;                                   // 8192

    pack_kernel<<<736, 256, 0, stream>>>(wqkv, aw1, aw2, pw2, p0, p1, p2, p3);
    qkv_mfma_kernel<<<npts / 16, 64, 0, stream>>>(x, p0, qkv);
    attn_fused_kernel<<<npts / 4, 128, 0, stream>>>(pos, qkv,
                                                    pw1, pb1, pb2,
                                                    p1, p2, p3, ab1, out);
}

// Round 5
// 115.181 us; speedup vs baseline: 1.1766x; 1.1766x over previous
//
#include <hip/hip_runtime.h>
#include <math.h>

#define DIM 128
#define N_PTS 512
#define K_NEIGH 16
#define POS_HID 64
#define ATTN_HID 512

typedef __attribute__((ext_vector_type(8))) short short8;
typedef __attribute__((ext_vector_type(4))) float f32x4;
typedef unsigned short us;
typedef unsigned long long ull;

__device__ __forceinline__ us f2b(float f) {
    unsigned int u = __builtin_bit_cast(unsigned int, f);
    u += 0x7fffu + ((u >> 16) & 1u);          // RNE
    return (us)(u >> 16);
}

__device__ __forceinline__ ull shflx64(ull v, int m) {
    int lo = __shfl_xor((int)(unsigned int)v, m);
    int hi = __shfl_xor((int)(unsigned int)(v >> 32), m);
    return ((ull)(unsigned int)hi << 32) | (unsigned int)lo;
}

// ---------------------------------------------------------------------------
// Pack weights (fp32) -> bf16 B-fragment order for mfma_16x16x32_bf16:
// B[k][n] -> lane l=(k/8%4)*16+(n%16), elem j=k%8, frag=(ks*NT+nt);
// packed[(frag*64+l)*8+j].  p0=wqkv(128x384), p1=aw1(128x512),
// p2=aw2(512x128), p3=pw2(64x128).   [R2-proven]
// ---------------------------------------------------------------------------
__global__ void pack_kernel(const float* __restrict__ wqkv,
                            const float* __restrict__ aw1,
                            const float* __restrict__ aw2,
                            const float* __restrict__ pw2,
                            us* __restrict__ p0, us* __restrict__ p1,
                            us* __restrict__ p2, us* __restrict__ p3) {
    int t = blockIdx.x * 256 + threadIdx.x;
    if (t < 49152) {                        // wqkv: nt 0..23, ks 0..3
        int j = t & 7, l = (t >> 3) & 63, rem = t >> 9;
        int nt = rem % 24, ks = rem / 24;
        int k = ks * 32 + (l >> 4) * 8 + j, n = nt * 16 + (l & 15);
        p0[t] = f2b(wqkv[k * 384 + n]);
    } else if (t < 114688) {                // aw1: ks 0..3, nt 0..31
        int u = t - 49152;
        int j = u & 7, l = (u >> 3) & 63, nt = (u >> 9) & 31, ks = u >> 14;
        int k = ks * 32 + (l >> 4) * 8 + j, n = nt * 16 + (l & 15);
        p1[u] = f2b(aw1[k * ATTN_HID + n]);
    } else if (t < 180224) {                // aw2: ch 0..15, nt 0..7
        int u = t - 114688;
        int j = u & 7, l = (u >> 3) & 63, nt = (u >> 9) & 7, ch = u >> 12;
        int k = ch * 32 + (l >> 4) * 8 + j, n = nt * 16 + (l & 15);
        p2[u] = f2b(aw2[k * DIM + n]);
    } else if (t < 188416) {                // pw2: ks 0..1, nt 0..7
        int u = t - 180224;
        int j = u & 7, l = (u >> 3) & 63, nt = (u >> 9) & 7, ks = u >> 12;
        int k = ks * 32 + (l >> 4) * 8 + j, n = nt * 16 + (l & 15);
        p3[u] = f2b(pw2[k * DIM + n]);
    }
}

// ---------------------------------------------------------------------------
// qkv via MFMA: 64 blocks x 256 thr (4 waves). Block stages one 16-point
// x-tile in LDS (R2-proven staging+barrier), wave w computes nt = 6w..6w+5.
// ---------------------------------------------------------------------------
__global__ __launch_bounds__(256)
void qkv_mfma_kernel(const float* __restrict__ x,
                     const us* __restrict__ p0,
                     float* __restrict__ qkv) {
    __shared__ __align__(16) us xA[16][136];
    const int tid = threadIdx.x;
    const int w = tid >> 6, lane = tid & 63, quad = lane >> 4, lq = lane & 15;
    const int n0 = blockIdx.x * 16;
    const int b = n0 >> 9, nn = n0 & (N_PTS - 1);
#pragma unroll
    for (int rr = 0; rr < 8; ++rr) {
        int id = rr * 256 + tid;
        int d = id >> 4, i = id & 15;
        xA[i][d] = f2b(x[(size_t)(b * DIM + d) * N_PTS + nn + i]);
    }
    __syncthreads();
    short8 a[4];
#pragma unroll
    for (int ks = 0; ks < 4; ++ks)
        a[ks] = *(const short8*)&xA[lq][ks * 32 + quad * 8];
#pragma unroll
    for (int i = 0; i < 6; ++i) {
        int nt = w * 6 + i;
        f32x4 acc = {0.f, 0.f, 0.f, 0.f};
#pragma unroll
        for (int ks = 0; ks < 4; ++ks) {
            const short8 bf = *(const short8*)(p0 + (size_t)((ks * 24 + nt) * 64 + lane) * 8);
            acc = __builtin_amdgcn_mfma_f32_16x16x32_bf16(a[ks], bf, acc, 0, 0, 0);
        }
#pragma unroll
        for (int r = 0; r < 4; ++r)
            qkv[(size_t)(n0 + quad * 4 + r) * 384 + nt * 16 + lq] = acc[r];
    }
}

// ---------------------------------------------------------------------------
// Fused attention [R2 body + R3 topk]: 4 points/block, 1 point/wave, LDS
// strictly wave-partitioned, ZERO barriers. topk -> pos-MLP -> pe GEMM ->
// hin/vg -> interleaved layer1/layer2 MFMA chain -> shfl softmax -> store.
// ab2 skipped: softmax over k is invariant to a per-channel constant.
// ---------------------------------------------------------------------------
__global__ __launch_bounds__(256)
void attn_fused_kernel(const float* __restrict__ pos,
                       const float* __restrict__ qkv,
                       const float* __restrict__ pw1,
                       const float* __restrict__ pb1,
                       const float* __restrict__ pb2,
                       const us* __restrict__ p1,
                       const us* __restrict__ p2,
                       const us* __restrict__ p3,
                       const float* __restrict__ ab1,
                       float* __restrict__ out) {
    __shared__ __align__(16) us hinA[4][16][136];   // 17.4 KB, per-wave rows
    __shared__ __align__(16) us h1s[4][16][40];     //  5.1 KB, per-wave
    __shared__ int nbrs[4][16];                     //  256 B, per-wave

    const int tid = threadIdx.x;
    const int w = tid >> 6, lane = tid & 63, quad = lane >> 4, lq = lane & 15;
    const int g = blockIdx.x * 4 + w, b = g >> 9, n = g & (N_PTS - 1);

    // ---- top-16: u64 key = (dist_bits<<32)|j, butterfly min [R3-proven] ----
    {
        const float pix = pos[g * 3 + 0], piy = pos[g * 3 + 1], piz = pos[g * 3 + 2];
        float d2[8];
#pragma unroll
        for (int rr = 0; rr < 8; ++rr) {
            int j = rr * 64 + lane;
            float dx = pix - pos[(b * N_PTS + j) * 3 + 0];
            float dy = piy - pos[(b * N_PTS + j) * 3 + 1];
            float dz = piz - pos[(b * N_PTS + j) * 3 + 2];
            d2[rr] = dx * dx + dy * dy + dz * dz;
        }
        for (int r = 0; r < K_NEIGH; ++r) {
            ull key = ~0ULL;
#pragma unroll
            for (int rr = 0; rr < 8; ++rr) {
                unsigned int fb = __builtin_bit_cast(unsigned int, d2[rr]);
                ull k2 = ((ull)fb << 32) | (unsigned int)(rr * 64 + lane);
                key = k2 < key ? k2 : key;
            }
#pragma unroll
            for (int off = 32; off > 0; off >>= 1) {
                ull o = shflx64(key, off);
                key = o < key ? o : key;
            }
            unsigned int jw = (unsigned int)key;      // uniform post-butterfly
            if (lane == 0) nbrs[w][r] = (int)jw;
            if (lane == (int)(jw & 63)) d2[jw >> 6] = __builtin_inff();
        }
    }

    // ---- pos-MLP hidden -> A-frags (k = ks*32 + quad*8 + jj) ----
    short8 pha[2];
    {
        const int jn = nbrs[w][lq];
        float rx = pos[g * 3 + 0] - pos[(b * N_PTS + jn) * 3 + 0];
        float ry = pos[g * 3 + 1] - pos[(b * N_PTS + jn) * 3 + 1];
        float rz = pos[g * 3 + 2] - pos[(b * N_PTS + jn) * 3 + 2];
#pragma unroll
        for (int ks = 0; ks < 2; ++ks) {
            short8 f;
#pragma unroll
            for (int jj = 0; jj < 8; ++jj) {
                int c = ks * 32 + quad * 8 + jj;
                float h = rx * pw1[c] + ry * pw1[64 + c] + rz * pw1[128 + c] + pb1[c];
                f[jj] = (short)f2b(fmaxf(h, 0.f));
            }
            pha[ks] = f;
        }
    }

    // ---- pe = ph @ pw2 + pb2 (M=16,K=64,N=128) ----
    f32x4 pe[8];
#pragma unroll
    for (int nt = 0; nt < 8; ++nt) {
        const short8 b0 = *(const short8*)(p3 + (size_t)((0 * 8 + nt) * 64 + lane) * 8);
        const short8 b1 = *(const short8*)(p3 + (size_t)((1 * 8 + nt) * 64 + lane) * 8);
        f32x4 acc = {0.f, 0.f, 0.f, 0.f};
        acc = __builtin_amdgcn_mfma_f32_16x16x32_bf16(pha[0], b0, acc, 0, 0, 0);
        acc = __builtin_amdgcn_mfma_f32_16x16x32_bf16(pha[1], b1, acc, 0, 0, 0);
        float bias = pb2[nt * 16 + lq];
#pragma unroll
        for (int r = 0; r < 4; ++r) pe[nt][r] = acc[r] + bias;
    }

    // ---- hin = q_i - k_j + pe -> LDS (bf16 A-layout); vg = v_j + pe ----
    f32x4 vg[8];
    {
        int jr[4];
#pragma unroll
        for (int r = 0; r < 4; ++r) jr[r] = nbrs[w][quad * 4 + r];
#pragma unroll
        for (int nt = 0; nt < 8; ++nt) {
            int d = nt * 16 + lq;
            float qv = qkv[(size_t)g * 384 + d];
#pragma unroll
            for (int r = 0; r < 4; ++r) {
                const float* kv = qkv + (size_t)(b * N_PTS + jr[r]) * 384;
                float pp = pe[nt][r];
                hinA[w][quad * 4 + r][d] = f2b(qv - kv[128 + d] + pp);
                vg[nt][r] = kv[256 + d] + pp;
            }
        }
    }

    // ---- layer1 + layer2 interleaved in 32-col chunks (per-wave) ----
    short8 a1f[4];
#pragma unroll
    for (int ks = 0; ks < 4; ++ks)
        a1f[ks] = *(const short8*)&hinA[w][lq][ks * 32 + quad * 8];

    f32x4 c2[8];
#pragma unroll
    for (int nt = 0; nt < 8; ++nt) c2[nt] = (f32x4){0.f, 0.f, 0.f, 0.f};

    for (int ch = 0; ch < 16; ++ch) {
        // all 8 p1 fragments for this chunk batched up front
        short8 bf[2][4];
#pragma unroll
        for (int t = 0; t < 2; ++t)
#pragma unroll
            for (int ks = 0; ks < 4; ++ks)
                bf[t][ks] = *(const short8*)(p1 + (size_t)(((ks << 5) + ch * 2 + t) * 64 + lane) * 8);
#pragma unroll
        for (int t = 0; t < 2; ++t) {
            int nt = ch * 2 + t;
            f32x4 acc = {0.f, 0.f, 0.f, 0.f};
#pragma unroll
            for (int ks = 0; ks < 4; ++ks)
                acc = __builtin_amdgcn_mfma_f32_16x16x32_bf16(a1f[ks], bf[t][ks], acc, 0, 0, 0);
            float bias = ab1[nt * 16 + lq];
#pragma unroll
            for (int r = 0; r < 4; ++r)
                h1s[w][quad * 4 + r][t * 16 + lq] = f2b(fmaxf(acc[r] + bias, 0.f));
        }
        const short8 a2 = *(const short8*)&h1s[w][lq][quad * 8];
#pragma unroll
        for (int nt2 = 0; nt2 < 8; ++nt2) {
            const short8 bf2 = *(const short8*)(p2 + (size_t)(((ch << 3) + nt2) * 64 + lane) * 8);
            c2[nt2] = __builtin_amdgcn_mfma_f32_16x16x32_bf16(a2, bf2, c2[nt2], 0, 0, 0);
        }
    }

    // ---- softmax over the 16 neighbors + aggregate + store ----
#pragma unroll
    for (int nt2 = 0; nt2 < 8; ++nt2) {
        f32x4 s4 = c2[nt2];
        float m = fmaxf(fmaxf(s4[0], s4[1]), fmaxf(s4[2], s4[3]));
        m = fmaxf(m, __shfl_xor(m, 16));
        m = fmaxf(m, __shfl_xor(m, 32));
        float e0 = __expf(s4[0] - m), e1 = __expf(s4[1] - m);
        float e2 = __expf(s4[2] - m), e3 = __expf(s4[3] - m);
        float s = e0 + e1 + e2 + e3;
        f32x4 v4 = vg[nt2];
        float a = e0 * v4[0] + e1 * v4[1] + e2 * v4[2] + e3 * v4[3];
        s += __shfl_xor(s, 16); s += __shfl_xor(s, 32);
        a += __shfl_xor(a, 16); a += __shfl_xor(a, 32);
        if (quad == 0)
            out[(size_t)(b * DIM + nt2 * 16 + lq) * N_PTS + n] = a / s;
    }
}

extern "C" void kernel_launch(void* const* d_in, const int* in_sizes, int n_in,
                              void* d_out, int out_size, void* d_ws, size_t ws_size,
                              hipStream_t stream) {
    const float* x    = (const float*)d_in[0];
    const float* pos  = (const float*)d_in[1];
    const float* wqkv = (const float*)d_in[2];
    const float* pw1  = (const float*)d_in[3];
    const float* pb1  = (const float*)d_in[4];
    const float* pw2  = (const float*)d_in[5];
    const float* pb2  = (const float*)d_in[6];
    const float* aw1  = (const float*)d_in[7];
    const float* ab1  = (const float*)d_in[8];
    const float* aw2  = (const float*)d_in[9];
    // ab2 unused: softmax over k is invariant to per-channel bias.
    float* out = (float*)d_out;

    int B = in_sizes[0] / (DIM * N_PTS);
    int npts = B * N_PTS;                    // 1024

    char* ws = (char*)d_ws;
    float* qkv = (float*)ws;                               // npts*384 f32
    us* p0 = (us*)(ws + (size_t)npts * 384 * 4);           // 49152
    us* p1 = p0 + 49152;                                   // 65536
    us* p2 = p1 + 65536;                                   // 65536
    us* p3 = p2 + 65536;                                   // 8192

    pack_kernel<<<736, 256, 0, stream>>>(wqkv, aw1, aw2, pw2, p0, p1, p2, p3);
    qkv_mfma_kernel<<<npts / 16, 256, 0, stream>>>(x, p0, qkv);
    attn_fused_kernel<<<npts / 4, 256, 0, stream>>>(pos, qkv,
                                                    pw1, pb1, pb2,
                                                    p1, p2, p3, ab1, out);
}

// Round 6
// 100.756 us; speedup vs baseline: 1.3450x; 1.1432x over previous
//
#include <hip/hip_runtime.h>
#include <math.h>

#define DIM 128
#define N_PTS 512
#define K_NEIGH 16
#define POS_HID 64
#define ATTN_HID 512

typedef __attribute__((ext_vector_type(8))) short short8;
typedef __attribute__((ext_vector_type(4))) float f32x4;
typedef unsigned short us;
typedef unsigned long long ull;

__device__ __forceinline__ us f2b(float f) {
    unsigned int u = __builtin_bit_cast(unsigned int, f);
    u += 0x7fffu + ((u >> 16) & 1u);          // RNE
    return (us)(u >> 16);
}

__device__ __forceinline__ ull shflx64(ull v, int m) {
    int lo = __shfl_xor((int)(unsigned int)v, m);
    int hi = __shfl_xor((int)(unsigned int)(v >> 32), m);
    return ((ull)(unsigned int)hi << 32) | (unsigned int)lo;
}

// ---------------------------------------------------------------------------
// Pack weights (fp32) -> bf16 B-fragment order for mfma_16x16x32_bf16:
// B[k][n] -> lane l=(k/8%4)*16+(n%16), elem j=k%8, frag=(ks*NT+nt);
// packed[(frag*64+l)*8+j].  p0=wqkv(128x384), p1=aw1(128x512),
// p2=aw2(512x128), p3=pw2(64x128).   [R2-proven]
// ---------------------------------------------------------------------------
__global__ void pack_kernel(const float* __restrict__ wqkv,
                            const float* __restrict__ aw1,
                            const float* __restrict__ aw2,
                            const float* __restrict__ pw2,
                            us* __restrict__ p0, us* __restrict__ p1,
                            us* __restrict__ p2, us* __restrict__ p3) {
    int t = blockIdx.x * 256 + threadIdx.x;
    if (t < 49152) {                        // wqkv: nt 0..23, ks 0..3
        int j = t & 7, l = (t >> 3) & 63, rem = t >> 9;
        int nt = rem % 24, ks = rem / 24;
        int k = ks * 32 + (l >> 4) * 8 + j, n = nt * 16 + (l & 15);
        p0[t] = f2b(wqkv[k * 384 + n]);
    } else if (t < 114688) {                // aw1: ks 0..3, nt 0..31
        int u = t - 49152;
        int j = u & 7, l = (u >> 3) & 63, nt = (u >> 9) & 31, ks = u >> 14;
        int k = ks * 32 + (l >> 4) * 8 + j, n = nt * 16 + (l & 15);
        p1[u] = f2b(aw1[k * ATTN_HID + n]);
    } else if (t < 180224) {                // aw2: ch 0..15, nt 0..7
        int u = t - 114688;
        int j = u & 7, l = (u >> 3) & 63, nt = (u >> 9) & 7, ch = u >> 12;
        int k = ch * 32 + (l >> 4) * 8 + j, n = nt * 16 + (l & 15);
        p2[u] = f2b(aw2[k * DIM + n]);
    } else if (t < 188416) {                // pw2: ks 0..1, nt 0..7
        int u = t - 180224;
        int j = u & 7, l = (u >> 3) & 63, nt = (u >> 9) & 7, ks = u >> 12;
        int k = ks * 32 + (l >> 4) * 8 + j, n = nt * 16 + (l & 15);
        p3[u] = f2b(pw2[k * DIM + n]);
    }
}

// ---------------------------------------------------------------------------
// qkv via MFMA: 64 blocks x 512 thr (8 waves). Block stages one 16-point
// x-tile in LDS (R5-proven staging+barrier), wave w computes nt = 3w..3w+2.
// ---------------------------------------------------------------------------
__global__ __launch_bounds__(512)
void qkv_mfma_kernel(const float* __restrict__ x,
                     const us* __restrict__ p0,
                     float* __restrict__ qkv) {
    __shared__ __align__(16) us xA[16][136];
    const int tid = threadIdx.x;
    const int w = tid >> 6, lane = tid & 63, quad = lane >> 4, lq = lane & 15;
    const int n0 = blockIdx.x * 16;
    const int b = n0 >> 9, nn = n0 & (N_PTS - 1);
#pragma unroll
    for (int rr = 0; rr < 4; ++rr) {
        int id = rr * 512 + tid;
        int d = id >> 4, i = id & 15;
        xA[i][d] = f2b(x[(size_t)(b * DIM + d) * N_PTS + nn + i]);
    }
    __syncthreads();
    short8 a[4];
#pragma unroll
    for (int ks = 0; ks < 4; ++ks)
        a[ks] = *(const short8*)&xA[lq][ks * 32 + quad * 8];
#pragma unroll
    for (int i = 0; i < 3; ++i) {
        int nt = w * 3 + i;
        f32x4 acc = {0.f, 0.f, 0.f, 0.f};
#pragma unroll
        for (int ks = 0; ks < 4; ++ks) {
            const short8 bf = *(const short8*)(p0 + (size_t)((ks * 24 + nt) * 64 + lane) * 8);
            acc = __builtin_amdgcn_mfma_f32_16x16x32_bf16(a[ks], bf, acc, 0, 0, 0);
        }
#pragma unroll
        for (int r = 0; r < 4; ++r)
            qkv[(size_t)(n0 + quad * 4 + r) * 384 + nt * 16 + lq] = acc[r];
    }
}

// ---------------------------------------------------------------------------
// Fused attention [R5 structure + ILP pipelining]: 4 points/block, 1 point/
// wave, LDS strictly wave-partitioned, ZERO barriers. All topk-independent
// loads hoisted before the topk (latency hides under its shuffle chain);
// ch-loop weight fragments double-buffered. Semantics identical to R5.
// ab2 skipped: softmax over k is invariant to a per-channel constant.
// ---------------------------------------------------------------------------
__global__ __launch_bounds__(256)
void attn_fused_kernel(const float* __restrict__ pos,
                       const float* __restrict__ qkv,
                       const float* __restrict__ pw1,
                       const float* __restrict__ pb1,
                       const float* __restrict__ pb2,
                       const us* __restrict__ p1,
                       const us* __restrict__ p2,
                       const us* __restrict__ p3,
                       const float* __restrict__ ab1,
                       float* __restrict__ out) {
    __shared__ __align__(16) us hinA[4][16][136];   // 17.4 KB, per-wave rows
    __shared__ __align__(16) us h1s[4][16][40];     //  5.1 KB, per-wave
    __shared__ int nbrs[4][16];                     //  256 B, per-wave

    const int tid = threadIdx.x;
    const int w = tid >> 6, lane = tid & 63, quad = lane >> 4, lq = lane & 15;
    const int g = blockIdx.x * 4 + w, b = g >> 9, n = g & (N_PTS - 1);

    // ==== hoisted loads: independent of topk, latency hides under it ====
    short8 b3f[2][8];                      // pw2 fragments
#pragma unroll
    for (int ks = 0; ks < 2; ++ks)
#pragma unroll
        for (int nt = 0; nt < 8; ++nt)
            b3f[ks][nt] = *(const short8*)(p3 + (size_t)((ks * 8 + nt) * 64 + lane) * 8);

    float w1x[2][8], w1y[2][8], w1z[2][8], w1b[2][8];   // pos-MLP layer-1 wts
#pragma unroll
    for (int ks = 0; ks < 2; ++ks)
#pragma unroll
        for (int jj = 0; jj < 8; ++jj) {
            int c = ks * 32 + quad * 8 + jj;
            w1x[ks][jj] = pw1[c];
            w1y[ks][jj] = pw1[64 + c];
            w1z[ks][jj] = pw1[128 + c];
            w1b[ks][jj] = pb1[c];
        }

    float qvr[8], pb2r[8];
#pragma unroll
    for (int nt = 0; nt < 8; ++nt) {
        qvr[nt]  = qkv[(size_t)g * 384 + nt * 16 + lq];
        pb2r[nt] = pb2[nt * 16 + lq];
    }

    // ---- top-16: u64 key = (dist_bits<<32)|j, butterfly min [R5-exact] ----
    {
        const float pix = pos[g * 3 + 0], piy = pos[g * 3 + 1], piz = pos[g * 3 + 2];
        float d2[8];
#pragma unroll
        for (int rr = 0; rr < 8; ++rr) {
            int j = rr * 64 + lane;
            float dx = pix - pos[(b * N_PTS + j) * 3 + 0];
            float dy = piy - pos[(b * N_PTS + j) * 3 + 1];
            float dz = piz - pos[(b * N_PTS + j) * 3 + 2];
            d2[rr] = dx * dx + dy * dy + dz * dz;
        }
        for (int r = 0; r < K_NEIGH; ++r) {
            ull key = ~0ULL;
#pragma unroll
            for (int rr = 0; rr < 8; ++rr) {
                unsigned int fb = __builtin_bit_cast(unsigned int, d2[rr]);
                ull k2 = ((ull)fb << 32) | (unsigned int)(rr * 64 + lane);
                key = k2 < key ? k2 : key;
            }
#pragma unroll
            for (int off = 32; off > 0; off >>= 1) {
                ull o = shflx64(key, off);
                key = o < key ? o : key;
            }
            unsigned int jw = (unsigned int)key;      // uniform post-butterfly
            if (lane == 0) nbrs[w][r] = (int)jw;
            if (lane == (int)(jw & 63)) d2[jw >> 6] = __builtin_inff();
        }
    }

    // ---- pos-MLP hidden -> A-frags (k = ks*32 + quad*8 + jj) ----
    short8 pha[2];
    {
        const int jn = nbrs[w][lq];
        float rx = pos[g * 3 + 0] - pos[(b * N_PTS + jn) * 3 + 0];
        float ry = pos[g * 3 + 1] - pos[(b * N_PTS + jn) * 3 + 1];
        float rz = pos[g * 3 + 2] - pos[(b * N_PTS + jn) * 3 + 2];
#pragma unroll
        for (int ks = 0; ks < 2; ++ks) {
            short8 f;
#pragma unroll
            for (int jj = 0; jj < 8; ++jj) {
                float h = rx * w1x[ks][jj] + ry * w1y[ks][jj] + rz * w1z[ks][jj] + w1b[ks][jj];
                f[jj] = (short)f2b(fmaxf(h, 0.f));
            }
            pha[ks] = f;
        }
    }

    // ---- pe = ph @ pw2 + pb2 (M=16,K=64,N=128) ----
    f32x4 pe[8];
#pragma unroll
    for (int nt = 0; nt < 8; ++nt) {
        f32x4 acc = {0.f, 0.f, 0.f, 0.f};
        acc = __builtin_amdgcn_mfma_f32_16x16x32_bf16(pha[0], b3f[0][nt], acc, 0, 0, 0);
        acc = __builtin_amdgcn_mfma_f32_16x16x32_bf16(pha[1], b3f[1][nt], acc, 0, 0, 0);
#pragma unroll
        for (int r = 0; r < 4; ++r) pe[nt][r] = acc[r] + pb2r[nt];
    }

    // ---- hin = q_i - k_j + pe -> LDS (bf16 A-layout); vg = v_j + pe ----
    f32x4 vg[8];
    {
        int jr[4];
#pragma unroll
        for (int r = 0; r < 4; ++r) jr[r] = nbrs[w][quad * 4 + r];
#pragma unroll
        for (int nt = 0; nt < 8; ++nt) {
            int d = nt * 16 + lq;
#pragma unroll
            for (int r = 0; r < 4; ++r) {
                const float* kv = qkv + (size_t)(b * N_PTS + jr[r]) * 384;
                float pp = pe[nt][r];
                hinA[w][quad * 4 + r][d] = f2b(qvr[nt] - kv[128 + d] + pp);
                vg[nt][r] = kv[256 + d] + pp;
            }
        }
    }

    // ---- layer1 + layer2, 32-col chunks, double-buffered weight frags ----
    short8 a1f[4];
#pragma unroll
    for (int ks = 0; ks < 4; ++ks)
        a1f[ks] = *(const short8*)&hinA[w][lq][ks * 32 + quad * 8];

    f32x4 c2[8];
#pragma unroll
    for (int nt = 0; nt < 8; ++nt) c2[nt] = (f32x4){0.f, 0.f, 0.f, 0.f};

    short8 p1f[2][2][4];   // [buf][t][ks]
    short8 p2f[2][8];      // [buf][nt2]
#pragma unroll
    for (int t = 0; t < 2; ++t)
#pragma unroll
        for (int ks = 0; ks < 4; ++ks)
            p1f[0][t][ks] = *(const short8*)(p1 + (size_t)(((ks << 5) + t) * 64 + lane) * 8);
#pragma unroll
    for (int nt2 = 0; nt2 < 8; ++nt2)
        p2f[0][nt2] = *(const short8*)(p2 + (size_t)(nt2 * 64 + lane) * 8);

#pragma unroll
    for (int ch = 0; ch < 16; ++ch) {
        const int cur = ch & 1, nxt = cur ^ 1;
        if (ch < 15) {                      // prefetch next chunk's layer1 wts
#pragma unroll
            for (int t = 0; t < 2; ++t)
#pragma unroll
                for (int ks = 0; ks < 4; ++ks)
                    p1f[nxt][t][ks] = *(const short8*)(p1 + (size_t)(((ks << 5) + (ch + 1) * 2 + t) * 64 + lane) * 8);
        }
#pragma unroll
        for (int t = 0; t < 2; ++t) {
            int nt = ch * 2 + t;
            f32x4 acc = {0.f, 0.f, 0.f, 0.f};
#pragma unroll
            for (int ks = 0; ks < 4; ++ks)
                acc = __builtin_amdgcn_mfma_f32_16x16x32_bf16(a1f[ks], p1f[cur][t][ks], acc, 0, 0, 0);
            float bias = ab1[nt * 16 + lq];
#pragma unroll
            for (int r = 0; r < 4; ++r)
                h1s[w][quad * 4 + r][t * 16 + lq] = f2b(fmaxf(acc[r] + bias, 0.f));
        }
        if (ch < 15) {                      // prefetch next chunk's layer2 wts
#pragma unroll
            for (int nt2 = 0; nt2 < 8; ++nt2)
                p2f[nxt][nt2] = *(const short8*)(p2 + (size_t)((((ch + 1) << 3) + nt2) * 64 + lane) * 8);
        }
        const short8 a2 = *(const short8*)&h1s[w][lq][quad * 8];
#pragma unroll
        for (int nt2 = 0; nt2 < 8; ++nt2)
            c2[nt2] = __builtin_amdgcn_mfma_f32_16x16x32_bf16(a2, p2f[cur][nt2], c2[nt2], 0, 0, 0);
    }

    // ---- softmax over the 16 neighbors + aggregate + store ----
#pragma unroll
    for (int nt2 = 0; nt2 < 8; ++nt2) {
        f32x4 s4 = c2[nt2];
        float m = fmaxf(fmaxf(s4[0], s4[1]), fmaxf(s4[2], s4[3]));
        m = fmaxf(m, __shfl_xor(m, 16));
        m = fmaxf(m, __shfl_xor(m, 32));
        float e0 = __expf(s4[0] - m), e1 = __expf(s4[1] - m);
        float e2 = __expf(s4[2] - m), e3 = __expf(s4[3] - m);
        float s = e0 + e1 + e2 + e3;
        f32x4 v4 = vg[nt2];
        float a = e0 * v4[0] + e1 * v4[1] + e2 * v4[2] + e3 * v4[3];
        s += __shfl_xor(s, 16); s += __shfl_xor(s, 32);
        a += __shfl_xor(a, 16); a += __shfl_xor(a, 32);
        if (quad == 0)
            out[(size_t)(b * DIM + nt2 * 16 + lq) * N_PTS + n] = a / s;
    }
}

extern "C" void kernel_launch(void* const* d_in, const int* in_sizes, int n_in,
                              void* d_out, int out_size, void* d_ws, size_t ws_size,
                              hipStream_t stream) {
    const float* x    = (const float*)d_in[0];
    const float* pos  = (const float*)d_in[1];
    const float* wqkv = (const float*)d_in[2];
    const float* pw1  = (const float*)d_in[3];
    const float* pb1  = (const float*)d_in[4];
    const float* pw2  = (const float*)d_in[5];
    const float* pb2  = (const float*)d_in[6];
    const float* aw1  = (const float*)d_in[7];
    const float* ab1  = (const float*)d_in[8];
    const float* aw2  = (const float*)d_in[9];
    // ab2 unused: softmax over k is invariant to per-channel bias.
    float* out = (float*)d_out;

    int B = in_sizes[0] / (DIM * N_PTS);
    int npts = B * N_PTS;                    // 1024

    char* ws = (char*)d_ws;
    float* qkv = (float*)ws;                               // npts*384 f32
    us* p0 = (us*)(ws + (size_t)npts * 384 * 4);           // 49152
    us* p1 = p0 + 49152;                                   // 65536
    us* p2 = p1 + 65536;                                   // 65536
    us* p3 = p2 + 65536;                                   // 8192

    pack_kernel<<<736, 256, 0, stream>>>(wqkv, aw1, aw2, pw2, p0, p1, p2, p3);
    qkv_mfma_kernel<<<npts / 16, 512, 0, stream>>>(x, p0, qkv);
    attn_fused_kernel<<<npts / 4, 256, 0, stream>>>(pos, qkv,
                                                    pw1, pb1, pb2,
                                                    p1, p2, p3, ab1, out);
}

// Round 7
// 100.000 us; speedup vs baseline: 1.3552x; 1.0076x over previous
//
#include <hip/hip_runtime.h>
#include <math.h>

#define DIM 128
#define N_PTS 512
#define K_NEIGH 16
#define POS_HID 64
#define ATTN_HID 512

typedef __attribute__((ext_vector_type(8))) short short8;
typedef __attribute__((ext_vector_type(4))) float f32x4;
typedef unsigned short us;
typedef unsigned long long ull;

__device__ __forceinline__ us f2b(float f) {
    unsigned int u = __builtin_bit_cast(unsigned int, f);
    u += 0x7fffu + ((u >> 16) & 1u);          // RNE
    return (us)(u >> 16);
}

__device__ __forceinline__ ull shflx64(ull v, int m) {
    int lo = __shfl_xor((int)(unsigned int)v, m);
    int hi = __shfl_xor((int)(unsigned int)(v >> 32), m);
    return ((ull)(unsigned int)hi << 32) | (unsigned int)lo;
}

// ---------------------------------------------------------------------------
// Pack weights (fp32) -> bf16 B-fragment order for mfma_16x16x32_bf16:
// B[k][n] -> lane l=(k/8%4)*16+(n%16), elem j=k%8, frag=(ks*NT+nt);
// packed[(frag*64+l)*8+j].  p0=wqkv(128x384), p1=aw1(128x512),
// p2=aw2(512x128), p3=pw2(64x128).   [R2-proven]
// ---------------------------------------------------------------------------
__global__ void pack_kernel(const float* __restrict__ wqkv,
                            const float* __restrict__ aw1,
                            const float* __restrict__ aw2,
                            const float* __restrict__ pw2,
                            us* __restrict__ p0, us* __restrict__ p1,
                            us* __restrict__ p2, us* __restrict__ p3) {
    int t = blockIdx.x * 256 + threadIdx.x;
    if (t < 49152) {                        // wqkv: nt 0..23, ks 0..3
        int j = t & 7, l = (t >> 3) & 63, rem = t >> 9;
        int nt = rem % 24, ks = rem / 24;
        int k = ks * 32 + (l >> 4) * 8 + j, n = nt * 16 + (l & 15);
        p0[t] = f2b(wqkv[k * 384 + n]);
    } else if (t < 114688) {                // aw1: ks 0..3, nt 0..31
        int u = t - 49152;
        int j = u & 7, l = (u >> 3) & 63, nt = (u >> 9) & 31, ks = u >> 14;
        int k = ks * 32 + (l >> 4) * 8 + j, n = nt * 16 + (l & 15);
        p1[u] = f2b(aw1[k * ATTN_HID + n]);
    } else if (t < 180224) {                // aw2: ch 0..15, nt 0..7
        int u = t - 114688;
        int j = u & 7, l = (u >> 3) & 63, nt = (u >> 9) & 7, ch = u >> 12;
        int k = ch * 32 + (l >> 4) * 8 + j, n = nt * 16 + (l & 15);
        p2[u] = f2b(aw2[k * DIM + n]);
    } else if (t < 188416) {                // pw2: ks 0..1, nt 0..7
        int u = t - 180224;
        int j = u & 7, l = (u >> 3) & 63, nt = (u >> 9) & 7, ks = u >> 12;
        int k = ks * 32 + (l >> 4) * 8 + j, n = nt * 16 + (l & 15);
        p3[u] = f2b(pw2[k * DIM + n]);
    }
}

// ---------------------------------------------------------------------------
// qkv via MFMA: 64 blocks x 512 thr (8 waves). Block stages one 16-point
// x-tile in LDS (R5-proven staging+barrier), wave w computes nt = 3w..3w+2.
// ---------------------------------------------------------------------------
__global__ __launch_bounds__(512)
void qkv_mfma_kernel(const float* __restrict__ x,
                     const us* __restrict__ p0,
                     float* __restrict__ qkv) {
    __shared__ __align__(16) us xA[16][136];
    const int tid = threadIdx.x;
    const int w = tid >> 6, lane = tid & 63, quad = lane >> 4, lq = lane & 15;
    const int n0 = blockIdx.x * 16;
    const int b = n0 >> 9, nn = n0 & (N_PTS - 1);
#pragma unroll
    for (int rr = 0; rr < 4; ++rr) {
        int id = rr * 512 + tid;
        int d = id >> 4, i = id & 15;
        xA[i][d] = f2b(x[(size_t)(b * DIM + d) * N_PTS + nn + i]);
    }
    __syncthreads();
    short8 a[4];
#pragma unroll
    for (int ks = 0; ks < 4; ++ks)
        a[ks] = *(const short8*)&xA[lq][ks * 32 + quad * 8];
#pragma unroll
    for (int i = 0; i < 3; ++i) {
        int nt = w * 3 + i;
        f32x4 acc = {0.f, 0.f, 0.f, 0.f};
#pragma unroll
        for (int ks = 0; ks < 4; ++ks) {
            const short8 bf = *(const short8*)(p0 + (size_t)((ks * 24 + nt) * 64 + lane) * 8);
            acc = __builtin_amdgcn_mfma_f32_16x16x32_bf16(a[ks], bf, acc, 0, 0, 0);
        }
#pragma unroll
        for (int r = 0; r < 4; ++r)
            qkv[(size_t)(n0 + quad * 4 + r) * 384 + nt * 16 + lq] = acc[r];
    }
}

// ---------------------------------------------------------------------------
// Fused attention [R6 structure + full VGPR budget]: 4 points/block, 1 point/
// wave, LDS strictly wave-partitioned, ZERO barriers. launch_bounds(256,1):
// at 1024 waves on 1024 SIMDs occupancy is 1 wave/SIMD no matter what, so an
// unrestricted VGPR budget (<=512) is free — prevents the R6 prefetch buffers
// from spilling to scratch. ab2 skipped (softmax invariant to per-ch bias).
// ---------------------------------------------------------------------------
__global__ __launch_bounds__(256, 1)
void attn_fused_kernel(const float* __restrict__ pos,
                       const float* __restrict__ qkv,
                       const float* __restrict__ pw1,
                       const float* __restrict__ pb1,
                       const float* __restrict__ pb2,
                       const us* __restrict__ p1,
                       const us* __restrict__ p2,
                       const us* __restrict__ p3,
                       const float* __restrict__ ab1,
                       float* __restrict__ out) {
    __shared__ __align__(16) us hinA[4][16][136];   // 17.4 KB, per-wave rows
    __shared__ __align__(16) us h1s[4][16][40];     //  5.1 KB, per-wave
    __shared__ int nbrs[4][16];                     //  256 B, per-wave

    const int tid = threadIdx.x;
    const int w = tid >> 6, lane = tid & 63, quad = lane >> 4, lq = lane & 15;
    const int g = blockIdx.x * 4 + w, b = g >> 9, n = g & (N_PTS - 1);

    // ==== hoisted loads: independent of topk, latency hides under it ====
    short8 b3f[2][8];                      // pw2 fragments
#pragma unroll
    for (int ks = 0; ks < 2; ++ks)
#pragma unroll
        for (int nt = 0; nt < 8; ++nt)
            b3f[ks][nt] = *(const short8*)(p3 + (size_t)((ks * 8 + nt) * 64 + lane) * 8);

    float w1x[2][8], w1y[2][8], w1z[2][8], w1b[2][8];   // pos-MLP layer-1 wts
#pragma unroll
    for (int ks = 0; ks < 2; ++ks)
#pragma unroll
        for (int jj = 0; jj < 8; ++jj) {
            int c = ks * 32 + quad * 8 + jj;
            w1x[ks][jj] = pw1[c];
            w1y[ks][jj] = pw1[64 + c];
            w1z[ks][jj] = pw1[128 + c];
            w1b[ks][jj] = pb1[c];
        }

    float qvr[8], pb2r[8], ab1r[32];
#pragma unroll
    for (int nt = 0; nt < 8; ++nt) {
        qvr[nt]  = qkv[(size_t)g * 384 + nt * 16 + lq];
        pb2r[nt] = pb2[nt * 16 + lq];
    }
#pragma unroll
    for (int nt = 0; nt < 32; ++nt) ab1r[nt] = ab1[nt * 16 + lq];

    // ---- top-16: u64 key = (dist_bits<<32)|j, butterfly min [R5-exact] ----
    {
        const float pix = pos[g * 3 + 0], piy = pos[g * 3 + 1], piz = pos[g * 3 + 2];
        float d2[8];
#pragma unroll
        for (int rr = 0; rr < 8; ++rr) {
            int j = rr * 64 + lane;
            float dx = pix - pos[(b * N_PTS + j) * 3 + 0];
            float dy = piy - pos[(b * N_PTS + j) * 3 + 1];
            float dz = piz - pos[(b * N_PTS + j) * 3 + 2];
            d2[rr] = dx * dx + dy * dy + dz * dz;
        }
        for (int r = 0; r < K_NEIGH; ++r) {
            ull key = ~0ULL;
#pragma unroll
            for (int rr = 0; rr < 8; ++rr) {
                unsigned int fb = __builtin_bit_cast(unsigned int, d2[rr]);
                ull k2 = ((ull)fb << 32) | (unsigned int)(rr * 64 + lane);
                key = k2 < key ? k2 : key;
            }
#pragma unroll
            for (int off = 32; off > 0; off >>= 1) {
                ull o = shflx64(key, off);
                key = o < key ? o : key;
            }
            unsigned int jw = (unsigned int)key;      // uniform post-butterfly
            if (lane == 0) nbrs[w][r] = (int)jw;
            if (lane == (int)(jw & 63)) d2[jw >> 6] = __builtin_inff();
        }
    }

    // ---- pos-MLP hidden -> A-frags (k = ks*32 + quad*8 + jj) ----
    short8 pha[2];
    {
        const int jn = nbrs[w][lq];
        float rx = pos[g * 3 + 0] - pos[(b * N_PTS + jn) * 3 + 0];
        float ry = pos[g * 3 + 1] - pos[(b * N_PTS + jn) * 3 + 1];
        float rz = pos[g * 3 + 2] - pos[(b * N_PTS + jn) * 3 + 2];
#pragma unroll
        for (int ks = 0; ks < 2; ++ks) {
            short8 f;
#pragma unroll
            for (int jj = 0; jj < 8; ++jj) {
                float h = rx * w1x[ks][jj] + ry * w1y[ks][jj] + rz * w1z[ks][jj] + w1b[ks][jj];
                f[jj] = (short)f2b(fmaxf(h, 0.f));
            }
            pha[ks] = f;
        }
    }

    // ---- pe = ph @ pw2 + pb2 (M=16,K=64,N=128) ----
    f32x4 pe[8];
#pragma unroll
    for (int nt = 0; nt < 8; ++nt) {
        f32x4 acc = {0.f, 0.f, 0.f, 0.f};
        acc = __builtin_amdgcn_mfma_f32_16x16x32_bf16(pha[0], b3f[0][nt], acc, 0, 0, 0);
        acc = __builtin_amdgcn_mfma_f32_16x16x32_bf16(pha[1], b3f[1][nt], acc, 0, 0, 0);
#pragma unroll
        for (int r = 0; r < 4; ++r) pe[nt][r] = acc[r] + pb2r[nt];
    }

    // ---- hin = q_i - k_j + pe -> LDS (bf16 A-layout); vg = v_j + pe ----
    f32x4 vg[8];
    {
        int jr[4];
#pragma unroll
        for (int r = 0; r < 4; ++r) jr[r] = nbrs[w][quad * 4 + r];
#pragma unroll
        for (int nt = 0; nt < 8; ++nt) {
            int d = nt * 16 + lq;
#pragma unroll
            for (int r = 0; r < 4; ++r) {
                const float* kv = qkv + (size_t)(b * N_PTS + jr[r]) * 384;
                float pp = pe[nt][r];
                hinA[w][quad * 4 + r][d] = f2b(qvr[nt] - kv[128 + d] + pp);
                vg[nt][r] = kv[256 + d] + pp;
            }
        }
    }

    // ---- layer1 + layer2, 32-col chunks, double-buffered weight frags ----
    short8 a1f[4];
#pragma unroll
    for (int ks = 0; ks < 4; ++ks)
        a1f[ks] = *(const short8*)&hinA[w][lq][ks * 32 + quad * 8];

    f32x4 c2[8];
#pragma unroll
    for (int nt = 0; nt < 8; ++nt) c2[nt] = (f32x4){0.f, 0.f, 0.f, 0.f};

    short8 p1f[2][2][4];   // [buf][t][ks]
    short8 p2f[2][8];      // [buf][nt2]
#pragma unroll
    for (int t = 0; t < 2; ++t)
#pragma unroll
        for (int ks = 0; ks < 4; ++ks)
            p1f[0][t][ks] = *(const short8*)(p1 + (size_t)(((ks << 5) + t) * 64 + lane) * 8);
#pragma unroll
    for (int nt2 = 0; nt2 < 8; ++nt2)
        p2f[0][nt2] = *(const short8*)(p2 + (size_t)(nt2 * 64 + lane) * 8);

#pragma unroll
    for (int ch = 0; ch < 16; ++ch) {
        const int cur = ch & 1, nxt = cur ^ 1;
        if (ch < 15) {                      // prefetch next chunk's layer1 wts
#pragma unroll
            for (int t = 0; t < 2; ++t)
#pragma unroll
                for (int ks = 0; ks < 4; ++ks)
                    p1f[nxt][t][ks] = *(const short8*)(p1 + (size_t)(((ks << 5) + (ch + 1) * 2 + t) * 64 + lane) * 8);
        }
#pragma unroll
        for (int t = 0; t < 2; ++t) {
            int nt = ch * 2 + t;
            f32x4 acc = {0.f, 0.f, 0.f, 0.f};
#pragma unroll
            for (int ks = 0; ks < 4; ++ks)
                acc = __builtin_amdgcn_mfma_f32_16x16x32_bf16(a1f[ks], p1f[cur][t][ks], acc, 0, 0, 0);
            float bias = ab1r[nt];
#pragma unroll
            for (int r = 0; r < 4; ++r)
                h1s[w][quad * 4 + r][t * 16 + lq] = f2b(fmaxf(acc[r] + bias, 0.f));
        }
        if (ch < 15) {                      // prefetch next chunk's layer2 wts
#pragma unroll
            for (int nt2 = 0; nt2 < 8; ++nt2)
                p2f[nxt][nt2] = *(const short8*)(p2 + (size_t)((((ch + 1) << 3) + nt2) * 64 + lane) * 8);
        }
        const short8 a2 = *(const short8*)&h1s[w][lq][quad * 8];
#pragma unroll
        for (int nt2 = 0; nt2 < 8; ++nt2)
            c2[nt2] = __builtin_amdgcn_mfma_f32_16x16x32_bf16(a2, p2f[cur][nt2], c2[nt2], 0, 0, 0);
    }

    // ---- softmax over the 16 neighbors + aggregate + store ----
#pragma unroll
    for (int nt2 = 0; nt2 < 8; ++nt2) {
        f32x4 s4 = c2[nt2];
        float m = fmaxf(fmaxf(s4[0], s4[1]), fmaxf(s4[2], s4[3]));
        m = fmaxf(m, __shfl_xor(m, 16));
        m = fmaxf(m, __shfl_xor(m, 32));
        float e0 = __expf(s4[0] - m), e1 = __expf(s4[1] - m);
        float e2 = __expf(s4[2] - m), e3 = __expf(s4[3] - m);
        float s = e0 + e1 + e2 + e3;
        f32x4 v4 = vg[nt2];
        float a = e0 * v4[0] + e1 * v4[1] + e2 * v4[2] + e3 * v4[3];
        s += __shfl_xor(s, 16); s += __shfl_xor(s, 32);
        a += __shfl_xor(a, 16); a += __shfl_xor(a, 32);
        if (quad == 0)
            out[(size_t)(b * DIM + nt2 * 16 + lq) * N_PTS + n] = a / s;
    }
}

extern "C" void kernel_launch(void* const* d_in, const int* in_sizes, int n_in,
                              void* d_out, int out_size, void* d_ws, size_t ws_size,
                              hipStream_t stream) {
    const float* x    = (const float*)d_in[0];
    const float* pos  = (const float*)d_in[1];
    const float* wqkv = (const float*)d_in[2];
    const float* pw1  = (const float*)d_in[3];
    const float* pb1  = (const float*)d_in[4];
    const float* pw2  = (const float*)d_in[5];
    const float* pb2  = (const float*)d_in[6];
    const float* aw1  = (const float*)d_in[7];
    const float* ab1  = (const float*)d_in[8];
    const float* aw2  = (const float*)d_in[9];
    // ab2 unused: softmax over k is invariant to per-channel bias.
    float* out = (float*)d_out;

    int B = in_sizes[0] / (DIM * N_PTS);
    int npts = B * N_PTS;                    // 1024

    char* ws = (char*)d_ws;
    float* qkv = (float*)ws;                               // npts*384 f32
    us* p0 = (us*)(ws + (size_t)npts * 384 * 4);           // 49152
    us* p1 = p0 + 49152;                                   // 65536
    us* p2 = p1 + 65536;                                   // 65536
    us* p3 = p2 + 65536;                                   // 8192

    pack_kernel<<<736, 256, 0, stream>>>(wqkv, aw1, aw2, pw2, p0, p1, p2, p3);
    qkv_mfma_kernel<<<npts / 16, 512, 0, stream>>>(x, p0, qkv);
    attn_fused_kernel<<<npts / 4, 256, 0, stream>>>(pos, qkv,
                                                    pw1, pb1, pb2,
                                                    p1, p2, p3, ab1, out);
}